// Round 4
// baseline (1274.369 us; speedup 1.0000x reference)
//
#include <hip/hip_runtime.h>
#include <hip/hip_bf16.h>

typedef __bf16 bf16x8 __attribute__((ext_vector_type(8)));
typedef float  f32x4  __attribute__((ext_vector_type(4)));
typedef unsigned short u16;
typedef u16 u16x8 __attribute__((ext_vector_type(8)));

__device__ __forceinline__ u16 f2bf(float f) {
    unsigned u = __float_as_uint(f);
    u += 0x7FFFu + ((u >> 16) & 1u);
    return (u16)(u >> 16);
}
__device__ __forceinline__ float bf2f(u16 s) {
    return __uint_as_float(((unsigned)s) << 16);
}

// Stage 64x256 fp32 row-major tile -> bf16 LDS [64][256], XOR-swizzled rows.
__device__ __forceinline__ void stage_tile(const float* __restrict__ src, char* buf, int t) {
#pragma unroll
    for (int i = 0; i < 8; ++i) {
        int flat = i * 2048 + t * 8;
        float4 a = *(const float4*)(src + flat);
        float4 b = *(const float4*)(src + flat + 4);
        int row  = flat >> 8;
        int colb = (flat & 255) * 2;
        u16x8 v;
        v[0]=f2bf(a.x); v[1]=f2bf(a.y); v[2]=f2bf(a.z); v[3]=f2bf(a.w);
        v[4]=f2bf(b.x); v[5]=f2bf(b.y); v[6]=f2bf(b.z); v[7]=f2bf(b.w);
        *(u16x8*)(buf + row*512 + (colb ^ ((row & 7) << 4))) = v;
    }
}

// 64x256 @ 256x256 GEMM: A from swizzled LDS, B-fragments pre-packed in global.
__device__ __forceinline__ void gemm_tile(const char* buf, const u16* __restrict__ WB,
                                          int w, int l, f32x4 acc[4][4]) {
#pragma unroll
    for (int mt = 0; mt < 4; mt++)
#pragma unroll
        for (int nt = 0; nt < 4; nt++) acc[mt][nt] = (f32x4){0.f,0.f,0.f,0.f};
#pragma unroll
    for (int ks = 0; ks < 8; ks++) {
        bf16x8 bfrag[4];
#pragma unroll
        for (int nt = 0; nt < 4; nt++)
            bfrag[nt] = *(const bf16x8*)(WB + (((ks*16) + (w*4 + nt))*64 + l)*8);
        bf16x8 afrag[4];
#pragma unroll
        for (int mt = 0; mt < 4; mt++) {
            int row  = mt*16 + (l & 15);
            int colb = ks*64 + ((l >> 4) << 4);
            afrag[mt] = *(const bf16x8*)(buf + row*512 + (colb ^ ((row & 7) << 4)));
        }
#pragma unroll
        for (int mt = 0; mt < 4; mt++)
#pragma unroll
            for (int nt = 0; nt < 4; nt++)
                acc[mt][nt] = __builtin_amdgcn_mfma_f32_16x16x32_bf16(
                    afrag[mt], bfrag[nt], acc[mt][nt], 0, 0, 0);
    }
}

// ---- prep: repack big projection weights into bf16 MFMA-B-fragment layout ----
__global__ void k_prep(const float* __restrict__ Wa, const float* __restrict__ Wn,
                       u16* __restrict__ WaB, u16* __restrict__ WnB) {
    int i = blockIdx.x * 256 + threadIdx.x;
    int j = i & 7, l = (i >> 3) & 63, ntg = (i >> 9) & 15, ks = i >> 13;
    int n = ntg*16 + (l & 15), k = ks*32 + ((l >> 4) << 3) + j;
    WaB[i] = f2bf(Wa[n*256 + k]);
    WnB[i] = f2bf(Wn[n*256 + k]);
}

// ---- prep2: per-head fused weights. Wqk = (Wk^T @ Wq)/sqrt(32), Wvo = Wo @ Wv ----
__global__ void k_prep2(const float* __restrict__ Wq, const float* __restrict__ Wk,
                        const float* __restrict__ Wv, const float* __restrict__ Wo,
                        u16* __restrict__ WqkF, float* __restrict__ Wvo) {
    __shared__ float sWq[1024], sWk[1024], sWv[1024], sWo[1024], sQK[1024];
    const int h = blockIdx.x, t = threadIdx.x;
#pragma unroll
    for (int i = 0; i < 4; i++) {
        int idx = i*256 + t;
        sWq[idx] = Wq[h*1024 + idx]; sWk[idx] = Wk[h*1024 + idx];
        sWv[idx] = Wv[h*1024 + idx]; sWo[idx] = Wo[h*1024 + idx];
    }
    __syncthreads();
#pragma unroll
    for (int i = 0; i < 4; i++) {
        int idx = i*256 + t, f = idx >> 5, e = idx & 31;
        float a1 = 0.f, a2 = 0.f;
#pragma unroll
        for (int d = 0; d < 32; d++) {
            a1 += sWk[d*32 + f] * sWq[d*32 + e];
            a2 += sWo[f*32 + d] * sWv[d*32 + e];
        }
        sQK[f*32 + e] = a1 * 0.17677669529663687f;
        Wvo[h*1024 + idx] = a2;
    }
    __syncthreads();
    // fragment layout: idx2 = (nt*64+l)*8+j -> Wqk[n2][e], n2=nt*16+(l&15), e=(l>>4)*8+j
#pragma unroll
    for (int i = 0; i < 4; i++) {
        int idx2 = i*256 + t;
        int j = idx2 & 7, l = (idx2 >> 3) & 63, nt = idx2 >> 9;
        int n2 = nt*16 + (l & 15), e = ((l >> 4) << 3) + j;
        WqkF[h*1024 + idx2] = f2bf(sQK[n2*32 + e]);
    }
}

// ---- anchor kernel: h_anchor = LN(x@Wa^T+b)+ve ; qk = Wqk @ h_anchor ; gs = softplus ----
__global__ __launch_bounds__(256, 3) void k_anchor(
    const float* __restrict__ xa, const float* __restrict__ gl,
    const float* __restrict__ b_anc, const float* __restrict__ g_anc,
    const float* __restrict__ be_anc, const float* __restrict__ ve,
    const float* __restrict__ Wgeom, const float* __restrict__ bgeom,
    const u16* __restrict__ WaB, const u16* __restrict__ WqkF,
    float* __restrict__ ha, float* __restrict__ qkws, float* __restrict__ gsws) {
    __shared__ __align__(16) char smem[32768 + 2048];
    const int t = threadIdx.x, w = t >> 6, l = t & 63;
    const int b0 = blockIdx.x * 64;

    stage_tile(xa + (size_t)b0 * 256, smem, t);
    __syncthreads();

    f32x4 acc[4][4];
    gemm_tile(smem, WaB, w, l, acc);

    float bn[4];
#pragma unroll
    for (int nt = 0; nt < 4; nt++) bn[nt] = b_anc[w*64 + nt*16 + (l & 15)];
#pragma unroll
    for (int mt = 0; mt < 4; mt++)
#pragma unroll
        for (int nt = 0; nt < 4; nt++)
#pragma unroll
            for (int r = 0; r < 4; r++) acc[mt][nt][r] += bn[nt];

    float2* PART = (float2*)(smem + 32768);
#pragma unroll
    for (int mt = 0; mt < 4; mt++)
#pragma unroll
        for (int r = 0; r < 4; r++) {
            float s  = acc[mt][0][r] + acc[mt][1][r] + acc[mt][2][r] + acc[mt][3][r];
            float qq = acc[mt][0][r]*acc[mt][0][r] + acc[mt][1][r]*acc[mt][1][r]
                     + acc[mt][2][r]*acc[mt][2][r] + acc[mt][3][r]*acc[mt][3][r];
#pragma unroll
            for (int m2 = 1; m2 < 16; m2 <<= 1) { s += __shfl_xor(s, m2); qq += __shfl_xor(qq, m2); }
            if ((l & 15) == 0) PART[w*64 + mt*16 + ((l >> 4) << 2) + r] = make_float2(s, qq);
        }
    __syncthreads();

    float gg[4], bb2[4], vv[4];
#pragma unroll
    for (int nt = 0; nt < 4; nt++) {
        int col = w*64 + nt*16 + (l & 15);
        gg[nt] = g_anc[col]; bb2[nt] = be_anc[col];
        vv[nt] = ve[((nt & 1) << 4) + (l & 15)];
    }
#pragma unroll
    for (int mt = 0; mt < 4; mt++)
#pragma unroll
        for (int r = 0; r < 4; r++) {
            int row = mt*16 + ((l >> 4) << 2) + r;
            float2 p0 = PART[row], p1 = PART[64+row], p2 = PART[128+row], p3 = PART[192+row];
            float mean = (p0.x+p1.x+p2.x+p3.x) * (1.f/256.f);
            float var  = (p0.y+p1.y+p2.y+p3.y) * (1.f/256.f) - mean*mean;
            float rs   = rsqrtf(var + 1e-5f);
#pragma unroll
            for (int nt = 0; nt < 4; nt++) {
                int col = w*64 + nt*16 + (l & 15);
                float x = (acc[mt][nt][r] - mean)*rs*gg[nt] + bb2[nt] + vv[nt];
                ha[(size_t)(b0+row)*256 + col] = x;
                *(u16*)(smem + row*512 + ((col*2) ^ ((row & 7) << 4))) = f2bf(x);
            }
        }
    __syncthreads();

    // qk projection (2 heads/wave): qk = Wqk @ h_anchor (scale folded into WqkF)
#pragma unroll
    for (int hh = 0; hh < 2; hh++) {
        int h = 2*w + hh;
        bf16x8 af[4];
#pragma unroll
        for (int mt = 0; mt < 4; mt++) {
            int row = mt*16 + (l & 15);
            int colb = h*64 + ((l >> 4) << 4);
            af[mt] = *(const bf16x8*)(smem + row*512 + (colb ^ ((row & 7) << 4)));
        }
        bf16x8 bf0 = *(const bf16x8*)(WqkF + ((h*2 + 0)*64 + l)*8);
        bf16x8 bf1 = *(const bf16x8*)(WqkF + ((h*2 + 1)*64 + l)*8);
        f32x4 qa[4][2];
#pragma unroll
        for (int mt = 0; mt < 4; mt++) {
            qa[mt][0] = (f32x4){0.f,0.f,0.f,0.f};
            qa[mt][1] = (f32x4){0.f,0.f,0.f,0.f};
            qa[mt][0] = __builtin_amdgcn_mfma_f32_16x16x32_bf16(af[mt], bf0, qa[mt][0], 0,0,0);
            qa[mt][1] = __builtin_amdgcn_mfma_f32_16x16x32_bf16(af[mt], bf1, qa[mt][1], 0,0,0);
        }
#pragma unroll
        for (int mt = 0; mt < 4; mt++)
#pragma unroll
            for (int nt = 0; nt < 2; nt++)
#pragma unroll
                for (int r = 0; r < 4; r++) {
                    int row = mt*16 + ((l >> 4) << 2) + r;
                    int d = nt*16 + (l & 15);
                    qkws[(size_t)(b0+row)*256 + h*32 + d] = qa[mt][nt][r];
                }
    }

    // geom_scale = softplus(g_local @ Wg^T + bg)
    for (int task = t; task < 512; task += 256) {
        int row = task >> 3, h = task & 7;
        const float* g = gl + (size_t)(b0+row)*32;
        float x = bgeom[h];
#pragma unroll
        for (int e = 0; e < 32; e++) x += g[e] * Wgeom[h*32 + e];
        gsws[(size_t)(b0+row)*8 + h] = (x > 20.f) ? x : log1pf(__expf(x));
    }
}

// ---- main kernel: ROWS rows per block, software-pipelined staging ----
#define ROWS 4
__global__ __launch_bounds__(256, 3) void k_main(
    const float* __restrict__ xn, const float* __restrict__ ew,
    const float* __restrict__ b_nei, const float* __restrict__ g_nei,
    const float* __restrict__ be_nei,
    const float* __restrict__ Wvo, const u16* __restrict__ WnB,
    const float* __restrict__ ha, const float* __restrict__ qkws,
    const float* __restrict__ gsws, float* __restrict__ outp, int Btot) {
    __shared__ __align__(16) char smem[32768 + 2048 + 1024 + 1024];
    float* PART_AT = (float*)(smem + 32768);      // 2 KB: LN partials, then attn [8][64]
    float* ZBUF    = (float*)(smem + 32768+2048); // 1 KB: z[256]
    float* QKB     = (float*)(smem + 32768+3072); // 1 KB: qk[256]
    const int t = threadIdx.x, w = t >> 6, l = t & 63;
    const int b0 = blockIdx.x * ROWS;
    const float4* src4 = (const float4*)xn;
    const size_t ATT_OFF = (size_t)Btot * 256;

    float4 st[16]; float4 qkp;
    // prologue: issue row 0 loads
    {
        size_t B4 = (size_t)b0 * 4096;
#pragma unroll
        for (int i = 0; i < 8; i++) {
            st[2*i]   = src4[B4 + i*512 + t*2];
            st[2*i+1] = src4[B4 + i*512 + t*2 + 1];
        }
        if (t < 64) qkp = ((const float4*)qkws)[(size_t)b0*64 + t];
    }

#pragma unroll
    for (int r = 0; r < ROWS; r++) {
        const int b = b0 + r;
        // ---- tile write (cvt_pk bf16, swizzled) ----
#pragma unroll
        for (int i = 0; i < 8; i++) {
            int flat = i*2048 + t*8;
            int row = flat >> 8, colb = (flat & 255) * 2;
            float4 a = st[2*i], c = st[2*i+1];
            unsigned p0, p1, p2, p3;
            asm("v_cvt_pk_bf16_f32 %0,%1,%2" : "=v"(p0) : "v"(a.x), "v"(a.y));
            asm("v_cvt_pk_bf16_f32 %0,%1,%2" : "=v"(p1) : "v"(a.z), "v"(a.w));
            asm("v_cvt_pk_bf16_f32 %0,%1,%2" : "=v"(p2) : "v"(c.x), "v"(c.y));
            asm("v_cvt_pk_bf16_f32 %0,%1,%2" : "=v"(p3) : "v"(c.z), "v"(c.w));
            *(uint4*)(smem + row*512 + (colb ^ ((row & 7) << 4))) = make_uint4(p0, p1, p2, p3);
        }
        if (t < 64) ((float4*)QKB)[t] = qkp;
        __syncthreads();  // B1: tile + qk ready

        // issue first half of next row's loads (hidden under GEMM)
        if (r + 1 < ROWS) {
            size_t B4 = (size_t)(b+1) * 4096;
#pragma unroll
            for (int i = 0; i < 4; i++) {
                st[2*i]   = src4[B4 + i*512 + t*2];
                st[2*i+1] = src4[B4 + i*512 + t*2 + 1];
            }
            if (t < 64) qkp = ((const float4*)qkws)[(size_t)(b+1)*64 + t];
        }

        // ---- GEMM + bias ----
        f32x4 acc[4][4];
        gemm_tile(smem, WnB, w, l, acc);
        float bn[4];
#pragma unroll
        for (int nt = 0; nt < 4; nt++) bn[nt] = b_nei[w*64 + nt*16 + (l & 15)];
#pragma unroll
        for (int mt = 0; mt < 4; mt++)
#pragma unroll
            for (int nt = 0; nt < 4; nt++)
#pragma unroll
                for (int rr = 0; rr < 4; rr++) acc[mt][nt][rr] += bn[nt];

        // ---- LN partials ----
        float2* PART = (float2*)PART_AT;
#pragma unroll
        for (int mt = 0; mt < 4; mt++)
#pragma unroll
            for (int rr = 0; rr < 4; rr++) {
                float s  = acc[mt][0][rr] + acc[mt][1][rr] + acc[mt][2][rr] + acc[mt][3][rr];
                float qq = acc[mt][0][rr]*acc[mt][0][rr] + acc[mt][1][rr]*acc[mt][1][rr]
                         + acc[mt][2][rr]*acc[mt][2][rr] + acc[mt][3][rr]*acc[mt][3][rr];
#pragma unroll
                for (int m2 = 1; m2 < 16; m2 <<= 1) { s += __shfl_xor(s, m2); qq += __shfl_xor(qq, m2); }
                if ((l & 15) == 0) PART[w*64 + mt*16 + ((l >> 4) << 2) + rr] = make_float2(s, qq);
            }
        __syncthreads();  // B2: partials ready

        // ---- LN finalize + writeback into tile ----
        float gg[4], bb2[4];
#pragma unroll
        for (int nt = 0; nt < 4; nt++) {
            int col = w*64 + nt*16 + (l & 15);
            gg[nt] = g_nei[col]; bb2[nt] = be_nei[col];
        }
#pragma unroll
        for (int mt = 0; mt < 4; mt++)
#pragma unroll
            for (int rr = 0; rr < 4; rr++) {
                int row = mt*16 + ((l >> 4) << 2) + rr;
                float2 p0 = PART[row], p1 = PART[64+row], p2 = PART[128+row], p3 = PART[192+row];
                float mean = (p0.x+p1.x+p2.x+p3.x) * (1.f/256.f);
                float var  = (p0.y+p1.y+p2.y+p3.y) * (1.f/256.f) - mean*mean;
                float rs   = rsqrtf(var + 1e-5f);
#pragma unroll
                for (int nt = 0; nt < 4; nt++) {
                    int col = w*64 + nt*16 + (l & 15);
                    float x = (acc[mt][nt][rr] - mean)*rs*gg[nt] + bb2[nt];
                    *(u16*)(smem + row*512 + ((col*2) ^ ((row & 7) << 4))) = f2bf(x);
                }
            }

        // issue second half of next row's loads (hidden under scores/z)
        if (r + 1 < ROWS) {
            size_t B4 = (size_t)(b+1) * 4096;
#pragma unroll
            for (int i = 4; i < 8; i++) {
                st[2*i]   = src4[B4 + i*512 + t*2];
                st[2*i+1] = src4[B4 + i*512 + t*2 + 1];
            }
        }
        __syncthreads();  // B3: h_nei ready

        // ---- scores + softmax (thread: h = t>>5, k in {t&31, (t&31)+32}) ----
        {
            const int h = t >> 5, k0 = t & 31;
            const float gsv = gsws[(size_t)b*8 + h];
            float4 q4[8];
#pragma unroll
            for (int j = 0; j < 8; j++) q4[j] = ((const float4*)QKB)[h*8 + j];
            float s0 = 0.f, s1 = 0.f;
            const int swz = (k0 & 7) << 4;
#pragma unroll
            for (int j = 0; j < 4; j++) {
                int colb = h*64 + j*16;
                u16x8 r0 = *(const u16x8*)(smem + k0*512       + (colb ^ swz));
                u16x8 r1 = *(const u16x8*)(smem + (k0+32)*512  + (colb ^ swz));
#pragma unroll
                for (int e = 0; e < 8; e++) {
                    float qv = ((const float*)q4)[j*8 + e];
                    s0 += bf2f(r0[e]) * qv;
                    s1 += bf2f(r1[e]) * qv;
                }
            }
            s0 += gsv * __logf(ew[(size_t)b*64 + k0] + 1e-6f);
            s1 += gsv * __logf(ew[(size_t)b*64 + k0 + 32] + 1e-6f);
            float mx = fmaxf(s0, s1);
#pragma unroll
            for (int m2 = 1; m2 < 32; m2 <<= 1) mx = fmaxf(mx, __shfl_xor(mx, m2));
            float e0 = __expf(s0 - mx), e1 = __expf(s1 - mx);
            float sm = e0 + e1;
#pragma unroll
            for (int m2 = 1; m2 < 32; m2 <<= 1) sm += __shfl_xor(sm, m2);
            float inv = 1.f / sm;
            e0 *= inv; e1 *= inv;
            PART_AT[h*64 + k0]      = e0;
            PART_AT[h*64 + k0 + 32] = e1;
            size_t ao = ATT_OFF + (size_t)b*512 + h*64;
            outp[ao + k0]      = e0;
            outp[ao + k0 + 32] = e1;
        }
        __syncthreads();  // B4: attn ready

        // ---- z = attn^T @ h_nei (thread t owns column t) ----
        {
            float z = 0.f;
            const float4* AT4 = (const float4*)PART_AT;
            const int hh = t >> 5;
#pragma unroll
            for (int kk = 0; kk < 16; kk++) {
                float4 a4 = AT4[hh*16 + kk];
#pragma unroll
                for (int q = 0; q < 4; q++) {
                    int k = kk*4 + q;
                    u16 hv = *(const u16*)(smem + k*512 + ((2*t) ^ ((k & 7) << 4)));
                    z += ((const float*)&a4)[q] * bf2f(hv);
                }
            }
            ZBUF[t] = z;
        }
        __syncthreads();  // B5: z ready

        // ---- o = Wvo_h @ z_h + h_anchor ----
        {
            const int h = t >> 5, oi = t & 31;
            const float4* wv4 = (const float4*)(Wvo + (h*32 + oi)*32);
            const float* zz = ZBUF + h*32;
            float o = 0.f;
#pragma unroll
            for (int e4 = 0; e4 < 8; e4++) {
                float4 wv = wv4[e4];
                o += wv.x*zz[e4*4] + wv.y*zz[e4*4+1] + wv.z*zz[e4*4+2] + wv.w*zz[e4*4+3];
            }
            o += ha[(size_t)b*256 + t];
            outp[(size_t)b*256 + t] = o;
        }
        // no barrier needed: next iteration writes tile/QKB which nobody reads now
    }
}

extern "C" void kernel_launch(void* const* d_in, const int* in_sizes, int n_in,
                              void* d_out, int out_size, void* d_ws, size_t ws_size,
                              hipStream_t stream) {
    const float* xa  = (const float*)d_in[0];
    const float* xn  = (const float*)d_in[1];
    const float* ew  = (const float*)d_in[2];
    const float* gl  = (const float*)d_in[3];
    const float* Wa  = (const float*)d_in[4];
    const float* ba  = (const float*)d_in[5];
    const float* ga  = (const float*)d_in[6];
    const float* bea = (const float*)d_in[7];
    const float* Wn  = (const float*)d_in[8];
    const float* bn  = (const float*)d_in[9];
    const float* gn  = (const float*)d_in[10];
    const float* ben = (const float*)d_in[11];
    const float* ve  = (const float*)d_in[12];
    const float* Wq  = (const float*)d_in[13];
    const float* Wk  = (const float*)d_in[14];
    const float* Wv  = (const float*)d_in[15];
    const float* Wo  = (const float*)d_in[16];
    const float* Wg  = (const float*)d_in[17];
    const float* bg  = (const float*)d_in[18];
    int B = in_sizes[0] / 256;

    char* ws = (char*)d_ws;
    u16*   WnB  = (u16*)(ws + 0);
    u16*   WaB  = (u16*)(ws + 131072);
    u16*   WqkF = (u16*)(ws + 262144);
    float* Wvo  = (float*)(ws + 278528);
    float* haP  = (float*)(ws + 311296);
    float* qkws = (float*)(ws + 311296 + 8388608);
    float* gsws = (float*)(ws + 311296 + 16777216);
    float* outp = (float*)d_out;

    hipLaunchKernelGGL(k_prep, dim3(256), dim3(256), 0, stream, Wa, Wn, WaB, WnB);
    hipLaunchKernelGGL(k_prep2, dim3(8), dim3(256), 0, stream, Wq, Wk, Wv, Wo, WqkF, Wvo);
    hipLaunchKernelGGL(k_anchor, dim3(B/64), dim3(256), 0, stream,
                       xa, gl, ba, ga, bea, ve, Wg, bg, WaB, WqkF, haP, qkws, gsws);
    hipLaunchKernelGGL(k_main, dim3(B/ROWS), dim3(256), 0, stream,
                       xn, ew, bn, gn, ben, Wvo, WnB, haP, qkws, gsws, outp, B);
}

// Round 5
// 1219.894 us; speedup vs baseline: 1.0447x; 1.0447x over previous
//
#include <hip/hip_runtime.h>
#include <hip/hip_bf16.h>

typedef __bf16 bf16x8 __attribute__((ext_vector_type(8)));
typedef float  f32x4  __attribute__((ext_vector_type(4)));
typedef unsigned short u16;
typedef u16 u16x8 __attribute__((ext_vector_type(8)));

__device__ __forceinline__ u16 f2bf(float f) {
    unsigned u = __float_as_uint(f);
    u += 0x7FFFu + ((u >> 16) & 1u);
    return (u16)(u >> 16);
}
__device__ __forceinline__ float bf2f(u16 s) {
    return __uint_as_float(((unsigned)s) << 16);
}

// Stage 64x256 fp32 row-major tile -> bf16 LDS [64][256], XOR-swizzled rows.
__device__ __forceinline__ void stage_tile(const float* __restrict__ src, char* buf, int t) {
#pragma unroll
    for (int i = 0; i < 8; ++i) {
        int flat = i * 2048 + t * 8;
        float4 a = *(const float4*)(src + flat);
        float4 b = *(const float4*)(src + flat + 4);
        int row  = flat >> 8;
        int colb = (flat & 255) * 2;
        u16x8 v;
        v[0]=f2bf(a.x); v[1]=f2bf(a.y); v[2]=f2bf(a.z); v[3]=f2bf(a.w);
        v[4]=f2bf(b.x); v[5]=f2bf(b.y); v[6]=f2bf(b.z); v[7]=f2bf(b.w);
        *(u16x8*)(buf + row*512 + (colb ^ ((row & 7) << 4))) = v;
    }
}

// 64x256 @ 256x256 GEMM: A from swizzled LDS, B-fragments pre-packed in global.
__device__ __forceinline__ void gemm_tile(const char* buf, const u16* __restrict__ WB,
                                          int w, int l, f32x4 acc[4][4]) {
#pragma unroll
    for (int mt = 0; mt < 4; mt++)
#pragma unroll
        for (int nt = 0; nt < 4; nt++) acc[mt][nt] = (f32x4){0.f,0.f,0.f,0.f};
#pragma unroll
    for (int ks = 0; ks < 8; ks++) {
        bf16x8 bfrag[4];
#pragma unroll
        for (int nt = 0; nt < 4; nt++)
            bfrag[nt] = *(const bf16x8*)(WB + (((ks*16) + (w*4 + nt))*64 + l)*8);
        bf16x8 afrag[4];
#pragma unroll
        for (int mt = 0; mt < 4; mt++) {
            int row  = mt*16 + (l & 15);
            int colb = ks*64 + ((l >> 4) << 4);
            afrag[mt] = *(const bf16x8*)(buf + row*512 + (colb ^ ((row & 7) << 4)));
        }
#pragma unroll
        for (int mt = 0; mt < 4; mt++)
#pragma unroll
            for (int nt = 0; nt < 4; nt++)
                acc[mt][nt] = __builtin_amdgcn_mfma_f32_16x16x32_bf16(
                    afrag[mt], bfrag[nt], acc[mt][nt], 0, 0, 0);
    }
}

// ---- prep: repack big projection weights into bf16 MFMA-B-fragment layout ----
__global__ void k_prep(const float* __restrict__ Wa, const float* __restrict__ Wn,
                       u16* __restrict__ WaB, u16* __restrict__ WnB) {
    int i = blockIdx.x * 256 + threadIdx.x;
    int j = i & 7, l = (i >> 3) & 63, ntg = (i >> 9) & 15, ks = i >> 13;
    int n = ntg*16 + (l & 15), k = ks*32 + ((l >> 4) << 3) + j;
    WaB[i] = f2bf(Wa[n*256 + k]);
    WnB[i] = f2bf(Wn[n*256 + k]);
}

// ---- prep2: per-head fused weights. Wqk = (Wk^T @ Wq)/sqrt(32), Wvo = Wo @ Wv ----
__global__ void k_prep2(const float* __restrict__ Wq, const float* __restrict__ Wk,
                        const float* __restrict__ Wv, const float* __restrict__ Wo,
                        u16* __restrict__ WqkF, float* __restrict__ Wvo) {
    __shared__ float sWq[1024], sWk[1024], sWv[1024], sWo[1024], sQK[1024];
    const int h = blockIdx.x, t = threadIdx.x;
#pragma unroll
    for (int i = 0; i < 4; i++) {
        int idx = i*256 + t;
        sWq[idx] = Wq[h*1024 + idx]; sWk[idx] = Wk[h*1024 + idx];
        sWv[idx] = Wv[h*1024 + idx]; sWo[idx] = Wo[h*1024 + idx];
    }
    __syncthreads();
#pragma unroll
    for (int i = 0; i < 4; i++) {
        int idx = i*256 + t, f = idx >> 5, e = idx & 31;
        float a1 = 0.f, a2 = 0.f;
#pragma unroll
        for (int d = 0; d < 32; d++) {
            a1 += sWk[d*32 + f] * sWq[d*32 + e];
            a2 += sWo[f*32 + d] * sWv[d*32 + e];
        }
        sQK[f*32 + e] = a1 * 0.17677669529663687f;
        Wvo[h*1024 + idx] = a2;
    }
    __syncthreads();
    // fragment layout: idx2 = (nt*64+l)*8+j -> Wqk[n2][e], n2=nt*16+(l&15), e=(l>>4)*8+j
#pragma unroll
    for (int i = 0; i < 4; i++) {
        int idx2 = i*256 + t;
        int j = idx2 & 7, l = (idx2 >> 3) & 63, nt = idx2 >> 9;
        int n2 = nt*16 + (l & 15), e = ((l >> 4) << 3) + j;
        WqkF[h*1024 + idx2] = f2bf(sQK[n2*32 + e]);
    }
}

// ---- anchor kernel: h_anchor = LN(x@Wa^T+b)+ve ; qk = Wqk @ h_anchor ; gs = softplus ----
__global__ __launch_bounds__(256, 3) void k_anchor(
    const float* __restrict__ xa, const float* __restrict__ gl,
    const float* __restrict__ b_anc, const float* __restrict__ g_anc,
    const float* __restrict__ be_anc, const float* __restrict__ ve,
    const float* __restrict__ Wgeom, const float* __restrict__ bgeom,
    const u16* __restrict__ WaB, const u16* __restrict__ WqkF,
    float* __restrict__ ha, float* __restrict__ qkws, float* __restrict__ gsws) {
    __shared__ __align__(16) char smem[32768 + 2048];
    const int t = threadIdx.x, w = t >> 6, l = t & 63;
    const int b0 = blockIdx.x * 64;

    stage_tile(xa + (size_t)b0 * 256, smem, t);
    __syncthreads();

    f32x4 acc[4][4];
    gemm_tile(smem, WaB, w, l, acc);

    float bn[4];
#pragma unroll
    for (int nt = 0; nt < 4; nt++) bn[nt] = b_anc[w*64 + nt*16 + (l & 15)];
#pragma unroll
    for (int mt = 0; mt < 4; mt++)
#pragma unroll
        for (int nt = 0; nt < 4; nt++)
#pragma unroll
            for (int r = 0; r < 4; r++) acc[mt][nt][r] += bn[nt];

    float2* PART = (float2*)(smem + 32768);
#pragma unroll
    for (int mt = 0; mt < 4; mt++)
#pragma unroll
        for (int r = 0; r < 4; r++) {
            float s  = acc[mt][0][r] + acc[mt][1][r] + acc[mt][2][r] + acc[mt][3][r];
            float qq = acc[mt][0][r]*acc[mt][0][r] + acc[mt][1][r]*acc[mt][1][r]
                     + acc[mt][2][r]*acc[mt][2][r] + acc[mt][3][r]*acc[mt][3][r];
#pragma unroll
            for (int m2 = 1; m2 < 16; m2 <<= 1) { s += __shfl_xor(s, m2); qq += __shfl_xor(qq, m2); }
            if ((l & 15) == 0) PART[w*64 + mt*16 + ((l >> 4) << 2) + r] = make_float2(s, qq);
        }
    __syncthreads();

    float gg[4], bb2[4], vv[4];
#pragma unroll
    for (int nt = 0; nt < 4; nt++) {
        int col = w*64 + nt*16 + (l & 15);
        gg[nt] = g_anc[col]; bb2[nt] = be_anc[col];
        vv[nt] = ve[((nt & 1) << 4) + (l & 15)];
    }
#pragma unroll
    for (int mt = 0; mt < 4; mt++)
#pragma unroll
        for (int r = 0; r < 4; r++) {
            int row = mt*16 + ((l >> 4) << 2) + r;
            float2 p0 = PART[row], p1 = PART[64+row], p2 = PART[128+row], p3 = PART[192+row];
            float mean = (p0.x+p1.x+p2.x+p3.x) * (1.f/256.f);
            float var  = (p0.y+p1.y+p2.y+p3.y) * (1.f/256.f) - mean*mean;
            float rs   = rsqrtf(var + 1e-5f);
#pragma unroll
            for (int nt = 0; nt < 4; nt++) {
                int col = w*64 + nt*16 + (l & 15);
                float x = (acc[mt][nt][r] - mean)*rs*gg[nt] + bb2[nt] + vv[nt];
                ha[(size_t)(b0+row)*256 + col] = x;
                *(u16*)(smem + row*512 + ((col*2) ^ ((row & 7) << 4))) = f2bf(x);
            }
        }
    __syncthreads();

    // qk projection (2 heads/wave): qk = Wqk @ h_anchor (scale folded into WqkF)
#pragma unroll
    for (int hh = 0; hh < 2; hh++) {
        int h = 2*w + hh;
        bf16x8 af[4];
#pragma unroll
        for (int mt = 0; mt < 4; mt++) {
            int row = mt*16 + (l & 15);
            int colb = h*64 + ((l >> 4) << 4);
            af[mt] = *(const bf16x8*)(smem + row*512 + (colb ^ ((row & 7) << 4)));
        }
        bf16x8 bf0 = *(const bf16x8*)(WqkF + ((h*2 + 0)*64 + l)*8);
        bf16x8 bf1 = *(const bf16x8*)(WqkF + ((h*2 + 1)*64 + l)*8);
        f32x4 qa[4][2];
#pragma unroll
        for (int mt = 0; mt < 4; mt++) {
            qa[mt][0] = (f32x4){0.f,0.f,0.f,0.f};
            qa[mt][1] = (f32x4){0.f,0.f,0.f,0.f};
            qa[mt][0] = __builtin_amdgcn_mfma_f32_16x16x32_bf16(af[mt], bf0, qa[mt][0], 0,0,0);
            qa[mt][1] = __builtin_amdgcn_mfma_f32_16x16x32_bf16(af[mt], bf1, qa[mt][1], 0,0,0);
        }
#pragma unroll
        for (int mt = 0; mt < 4; mt++)
#pragma unroll
            for (int nt = 0; nt < 2; nt++)
#pragma unroll
                for (int r = 0; r < 4; r++) {
                    int row = mt*16 + ((l >> 4) << 2) + r;
                    int d = nt*16 + (l & 15);
                    qkws[(size_t)(b0+row)*256 + h*32 + d] = qa[mt][nt][r];
                }
    }

    // geom_scale = softplus(g_local @ Wg^T + bg)
    for (int task = t; task < 512; task += 256) {
        int row = task >> 3, h = task & 7;
        const float* g = gl + (size_t)(b0+row)*32;
        float x = bgeom[h];
#pragma unroll
        for (int e = 0; e < 32; e++) x += g[e] * Wgeom[h*32 + e];
        gsws[(size_t)(b0+row)*8 + h] = (x > 20.f) ? x : log1pf(__expf(x));
    }
}

// ---- main kernel: ROWS rows/block; prefetch issued where acc is dead; z & o via shuffles ----
#define ROWS 4
__global__ __launch_bounds__(256, 3) void k_main(
    const float* __restrict__ xn, const float* __restrict__ ew,
    const float* __restrict__ b_nei, const float* __restrict__ g_nei,
    const float* __restrict__ be_nei,
    const float* __restrict__ Wvo, const u16* __restrict__ WnB,
    const float* __restrict__ ha, const float* __restrict__ qkws,
    const float* __restrict__ gsws, float* __restrict__ outp, int Btot) {
    __shared__ __align__(16) char smem[32768 + 2048 + 1024];
    float2* PART = (float2*)(smem + 32768);       // 2 KB: LN partials
    float*  QKB  = (float*)(smem + 32768 + 2048); // 1 KB: qk[256]
    const int t = threadIdx.x, w = t >> 6, l = t & 63;
    const int b0 = blockIdx.x * ROWS;
    const float4* src4 = (const float4*)xn;
    const size_t ATT_OFF = (size_t)Btot * 256;

    float4 st[16]; float4 qkp;
    {   // prologue: issue row 0 loads
        size_t B4a = (size_t)b0 * 4096;
#pragma unroll
        for (int i = 0; i < 8; i++) {
            st[2*i]   = src4[B4a + i*512 + t*2];
            st[2*i+1] = src4[B4a + i*512 + t*2 + 1];
        }
        if (t < 64) qkp = ((const float4*)qkws)[(size_t)b0*64 + t];
    }

#pragma unroll
    for (int r = 0; r < ROWS; r++) {
        const int b = b0 + r;
        // ---- tile write (cvt_pk bf16, swizzled); st dies here ----
#pragma unroll
        for (int i = 0; i < 8; i++) {
            int flat = i*2048 + t*8;
            int row = flat >> 8, colb = (flat & 255) * 2;
            float4 a = st[2*i], c = st[2*i+1];
            unsigned p0, p1, p2, p3;
            asm("v_cvt_pk_bf16_f32 %0,%1,%2" : "=v"(p0) : "v"(a.x), "v"(a.y));
            asm("v_cvt_pk_bf16_f32 %0,%1,%2" : "=v"(p1) : "v"(a.z), "v"(a.w));
            asm("v_cvt_pk_bf16_f32 %0,%1,%2" : "=v"(p2) : "v"(c.x), "v"(c.y));
            asm("v_cvt_pk_bf16_f32 %0,%1,%2" : "=v"(p3) : "v"(c.z), "v"(c.w));
            *(uint4*)(smem + row*512 + (colb ^ ((row & 7) << 4))) = make_uint4(p0, p1, p2, p3);
        }
        if (t < 64) ((float4*)QKB)[t] = qkp;
        __syncthreads();  // B1: tile + qk ready

        // ---- GEMM + bias (acc live) ----
        f32x4 acc[4][4];
        gemm_tile(smem, WnB, w, l, acc);
        float bn[4];
#pragma unroll
        for (int nt = 0; nt < 4; nt++) bn[nt] = b_nei[w*64 + nt*16 + (l & 15)];
#pragma unroll
        for (int mt = 0; mt < 4; mt++)
#pragma unroll
            for (int nt = 0; nt < 4; nt++)
#pragma unroll
                for (int rr = 0; rr < 4; rr++) acc[mt][nt][rr] += bn[nt];

        // ---- LN partials ----
#pragma unroll
        for (int mt = 0; mt < 4; mt++)
#pragma unroll
            for (int rr = 0; rr < 4; rr++) {
                float s  = acc[mt][0][rr] + acc[mt][1][rr] + acc[mt][2][rr] + acc[mt][3][rr];
                float qq = acc[mt][0][rr]*acc[mt][0][rr] + acc[mt][1][rr]*acc[mt][1][rr]
                         + acc[mt][2][rr]*acc[mt][2][rr] + acc[mt][3][rr]*acc[mt][3][rr];
#pragma unroll
                for (int m2 = 1; m2 < 16; m2 <<= 1) { s += __shfl_xor(s, m2); qq += __shfl_xor(qq, m2); }
                if ((l & 15) == 0) PART[w*64 + mt*16 + ((l >> 4) << 2) + rr] = make_float2(s, qq);
            }
        __syncthreads();  // B2: partials ready

        // ---- LN finalize + writeback into tile (acc dies here) ----
        float gg[4], bb2[4];
#pragma unroll
        for (int nt = 0; nt < 4; nt++) {
            int col = w*64 + nt*16 + (l & 15);
            gg[nt] = g_nei[col]; bb2[nt] = be_nei[col];
        }
#pragma unroll
        for (int mt = 0; mt < 4; mt++)
#pragma unroll
            for (int rr = 0; rr < 4; rr++) {
                int row = mt*16 + ((l >> 4) << 2) + rr;
                float2 p0 = PART[row], p1 = PART[64+row], p2 = PART[128+row], p3 = PART[192+row];
                float mean = (p0.x+p1.x+p2.x+p3.x) * (1.f/256.f);
                float var  = (p0.y+p1.y+p2.y+p3.y) * (1.f/256.f) - mean*mean;
                float rs   = rsqrtf(var + 1e-5f);
#pragma unroll
                for (int nt = 0; nt < 4; nt++) {
                    int col = w*64 + nt*16 + (l & 15);
                    float x = (acc[mt][nt][rr] - mean)*rs*gg[nt] + bb2[nt];
                    *(u16*)(smem + row*512 + ((col*2) ^ ((row & 7) << 4))) = f2bf(x);
                }
            }
        __syncthreads();  // B3: h_nei ready

        // ---- issue next row's loads NOW (acc dead; consumed after B4 at next tile-write;
        //      no intervening barrier until B4, which sits after ~1200cy of compute) ----
        if (r + 1 < ROWS) {
            size_t Bn = (size_t)(b+1) * 4096;
#pragma unroll
            for (int i = 0; i < 8; i++) {
                st[2*i]   = src4[Bn + i*512 + t*2];
                st[2*i+1] = src4[Bn + i*512 + t*2 + 1];
            }
            if (t < 64) qkp = ((const float4*)qkws)[(size_t)(b+1)*64 + t];
        }

        // ---- scores + softmax (h = t>>5 half-wave group; k in {t&31, (t&31)+32}) ----
        const int h = t >> 5, k0 = t & 31, base = t & 32;
        float e0, e1;
        {
            const float gsv = gsws[(size_t)b*8 + h];
            float s0 = 0.f, s1 = 0.f;
            const int swz = (k0 & 7) << 4;
#pragma unroll
            for (int j = 0; j < 4; j++) {
                int colb = h*64 + j*16;
                u16x8 r0 = *(const u16x8*)(smem + k0*512       + (colb ^ swz));
                u16x8 r1 = *(const u16x8*)(smem + (k0+32)*512  + (colb ^ swz));
                float4 qa = ((const float4*)QKB)[h*8 + j*2];
                float4 qb = ((const float4*)QKB)[h*8 + j*2 + 1];
                s0 += bf2f(r0[0])*qa.x + bf2f(r0[1])*qa.y + bf2f(r0[2])*qa.z + bf2f(r0[3])*qa.w
                    + bf2f(r0[4])*qb.x + bf2f(r0[5])*qb.y + bf2f(r0[6])*qb.z + bf2f(r0[7])*qb.w;
                s1 += bf2f(r1[0])*qa.x + bf2f(r1[1])*qa.y + bf2f(r1[2])*qa.z + bf2f(r1[3])*qa.w
                    + bf2f(r1[4])*qb.x + bf2f(r1[5])*qb.y + bf2f(r1[6])*qb.z + bf2f(r1[7])*qb.w;
            }
            s0 += gsv * __logf(ew[(size_t)b*64 + k0] + 1e-6f);
            s1 += gsv * __logf(ew[(size_t)b*64 + k0 + 32] + 1e-6f);
            float mx = fmaxf(s0, s1);
#pragma unroll
            for (int m2 = 1; m2 < 32; m2 <<= 1) mx = fmaxf(mx, __shfl_xor(mx, m2));
            e0 = __expf(s0 - mx); e1 = __expf(s1 - mx);
            float sm = e0 + e1;
#pragma unroll
            for (int m2 = 1; m2 < 32; m2 <<= 1) sm += __shfl_xor(sm, m2);
            float inv = 1.f / sm;
            e0 *= inv; e1 *= inv;
            size_t ao = ATT_OFF + (size_t)b*512 + h*64;
            outp[ao + k0]      = e0;
            outp[ao + k0 + 32] = e1;
        }

        // ---- z = attn^T @ h_nei via half-wave shuffles (no barrier, no LDS round-trip) ----
        float z = 0.f;
#pragma unroll
        for (int k = 0; k < 32; k++) {
            float a0 = __shfl(e0, base + k);
            float a1 = __shfl(e1, base + k);
            u16 h0 = *(const u16*)(smem + k*512      + ((2*t) ^ ((k & 7) << 4)));
            u16 h1 = *(const u16*)(smem + (k+32)*512 + ((2*t) ^ ((k & 7) << 4)));
            z += a0 * bf2f(h0) + a1 * bf2f(h1);
        }

        // ---- o = Wvo_h @ z_h + h_anchor via shuffles (z[h*32+d] is in lane base+d) ----
        {
            const float4* wv4 = (const float4*)(Wvo + (h*32 + k0)*32);
            float o = 0.f;
#pragma unroll
            for (int e4 = 0; e4 < 8; e4++) {
                float4 wv = wv4[e4];
                o += wv.x * __shfl(z, base + e4*4)
                   + wv.y * __shfl(z, base + e4*4 + 1)
                   + wv.z * __shfl(z, base + e4*4 + 2)
                   + wv.w * __shfl(z, base + e4*4 + 3);
            }
            o += ha[(size_t)b*256 + t];
            outp[(size_t)b*256 + t] = o;
        }
        __syncthreads();  // B4: all readers done before next tile-write (also drains prefetch)
    }
}

extern "C" void kernel_launch(void* const* d_in, const int* in_sizes, int n_in,
                              void* d_out, int out_size, void* d_ws, size_t ws_size,
                              hipStream_t stream) {
    const float* xa  = (const float*)d_in[0];
    const float* xn  = (const float*)d_in[1];
    const float* ew  = (const float*)d_in[2];
    const float* gl  = (const float*)d_in[3];
    const float* Wa  = (const float*)d_in[4];
    const float* ba  = (const float*)d_in[5];
    const float* ga  = (const float*)d_in[6];
    const float* bea = (const float*)d_in[7];
    const float* Wn  = (const float*)d_in[8];
    const float* bn  = (const float*)d_in[9];
    const float* gn  = (const float*)d_in[10];
    const float* ben = (const float*)d_in[11];
    const float* ve  = (const float*)d_in[12];
    const float* Wq  = (const float*)d_in[13];
    const float* Wk  = (const float*)d_in[14];
    const float* Wv  = (const float*)d_in[15];
    const float* Wo  = (const float*)d_in[16];
    const float* Wg  = (const float*)d_in[17];
    const float* bg  = (const float*)d_in[18];
    int B = in_sizes[0] / 256;

    char* ws = (char*)d_ws;
    u16*   WnB  = (u16*)(ws + 0);
    u16*   WaB  = (u16*)(ws + 131072);
    u16*   WqkF = (u16*)(ws + 262144);
    float* Wvo  = (float*)(ws + 278528);
    float* haP  = (float*)(ws + 311296);
    float* qkws = (float*)(ws + 311296 + 8388608);
    float* gsws = (float*)(ws + 311296 + 16777216);
    float* outp = (float*)d_out;

    hipLaunchKernelGGL(k_prep, dim3(256), dim3(256), 0, stream, Wa, Wn, WaB, WnB);
    hipLaunchKernelGGL(k_prep2, dim3(8), dim3(256), 0, stream, Wq, Wk, Wv, Wo, WqkF, Wvo);
    hipLaunchKernelGGL(k_anchor, dim3(B/64), dim3(256), 0, stream,
                       xa, gl, ba, ga, bea, ve, Wg, bg, WaB, WqkF, haP, qkws, gsws);
    hipLaunchKernelGGL(k_main, dim3(B/ROWS), dim3(256), 0, stream,
                       xn, ew, bn, gn, ben, Wvo, WnB, haP, qkws, gsws, outp, B);
}

// Round 8
// 1208.672 us; speedup vs baseline: 1.0544x; 1.0093x over previous
//
#include <hip/hip_runtime.h>
#include <hip/hip_bf16.h>

typedef __bf16 bf16x8 __attribute__((ext_vector_type(8)));
typedef float  f32x4  __attribute__((ext_vector_type(4)));
typedef unsigned short u16;
typedef u16 u16x8 __attribute__((ext_vector_type(8)));

__device__ __forceinline__ u16 f2bf(float f) {
    unsigned u = __float_as_uint(f);
    u += 0x7FFFu + ((u >> 16) & 1u);
    return (u16)(u >> 16);
}
__device__ __forceinline__ float bf2f(u16 s) {
    return __uint_as_float(((unsigned)s) << 16);
}

// Stage 64x256 fp32 row-major tile -> bf16 LDS [64][256], XOR-swizzled rows.
__device__ __forceinline__ void stage_tile(const float* __restrict__ src, char* buf, int t) {
#pragma unroll
    for (int i = 0; i < 8; ++i) {
        int flat = i * 2048 + t * 8;
        float4 a = *(const float4*)(src + flat);
        float4 b = *(const float4*)(src + flat + 4);
        int row  = flat >> 8;
        int colb = (flat & 255) * 2;
        u16x8 v;
        v[0]=f2bf(a.x); v[1]=f2bf(a.y); v[2]=f2bf(a.z); v[3]=f2bf(a.w);
        v[4]=f2bf(b.x); v[5]=f2bf(b.y); v[6]=f2bf(b.z); v[7]=f2bf(b.w);
        *(u16x8*)(buf + row*512 + (colb ^ ((row & 7) << 4))) = v;
    }
}

// 64x256 @ 256x256 GEMM: A from swizzled LDS, B-fragments pre-packed in global.
__device__ __forceinline__ void gemm_tile(const char* buf, const u16* __restrict__ WB,
                                          int w, int l, f32x4 acc[4][4]) {
#pragma unroll
    for (int mt = 0; mt < 4; mt++)
#pragma unroll
        for (int nt = 0; nt < 4; nt++) acc[mt][nt] = (f32x4){0.f,0.f,0.f,0.f};
#pragma unroll
    for (int ks = 0; ks < 8; ks++) {
        bf16x8 bfrag[4];
#pragma unroll
        for (int nt = 0; nt < 4; nt++)
            bfrag[nt] = *(const bf16x8*)(WB + (((ks*16) + (w*4 + nt))*64 + l)*8);
        bf16x8 afrag[4];
#pragma unroll
        for (int mt = 0; mt < 4; mt++) {
            int row  = mt*16 + (l & 15);
            int colb = ks*64 + ((l >> 4) << 4);
            afrag[mt] = *(const bf16x8*)(buf + row*512 + (colb ^ ((row & 7) << 4)));
        }
#pragma unroll
        for (int mt = 0; mt < 4; mt++)
#pragma unroll
            for (int nt = 0; nt < 4; nt++)
                acc[mt][nt] = __builtin_amdgcn_mfma_f32_16x16x32_bf16(
                    afrag[mt], bfrag[nt], acc[mt][nt], 0, 0, 0);
    }
}

// ---- prep: repack big projection weights into bf16 MFMA-B-fragment layout ----
__global__ void k_prep(const float* __restrict__ Wa, const float* __restrict__ Wn,
                       u16* __restrict__ WaB, u16* __restrict__ WnB) {
    int i = blockIdx.x * 256 + threadIdx.x;
    int j = i & 7, l = (i >> 3) & 63, ntg = (i >> 9) & 15, ks = i >> 13;
    int n = ntg*16 + (l & 15), k = ks*32 + ((l >> 4) << 3) + j;
    WaB[i] = f2bf(Wa[n*256 + k]);
    WnB[i] = f2bf(Wn[n*256 + k]);
}

// ---- prep2: per-head fused weights. Wqk = (Wk^T @ Wq)/sqrt(32), Wvo = Wo @ Wv ----
__global__ void k_prep2(const float* __restrict__ Wq, const float* __restrict__ Wk,
                        const float* __restrict__ Wv, const float* __restrict__ Wo,
                        u16* __restrict__ WqkF, float* __restrict__ Wvo) {
    __shared__ float sWq[1024], sWk[1024], sWv[1024], sWo[1024], sQK[1024];
    const int h = blockIdx.x, t = threadIdx.x;
#pragma unroll
    for (int i = 0; i < 4; i++) {
        int idx = i*256 + t;
        sWq[idx] = Wq[h*1024 + idx]; sWk[idx] = Wk[h*1024 + idx];
        sWv[idx] = Wv[h*1024 + idx]; sWo[idx] = Wo[h*1024 + idx];
    }
    __syncthreads();
#pragma unroll
    for (int i = 0; i < 4; i++) {
        int idx = i*256 + t, f = idx >> 5, e = idx & 31;
        float a1 = 0.f, a2 = 0.f;
#pragma unroll
        for (int d = 0; d < 32; d++) {
            a1 += sWk[d*32 + f] * sWq[d*32 + e];
            a2 += sWo[f*32 + d] * sWv[d*32 + e];
        }
        sQK[f*32 + e] = a1 * 0.17677669529663687f;
        Wvo[h*1024 + idx] = a2;
    }
    __syncthreads();
    // fragment layout: idx2 = (nt*64+l)*8+j -> Wqk[n2][e], n2=nt*16+(l&15), e=(l>>4)*8+j
#pragma unroll
    for (int i = 0; i < 4; i++) {
        int idx2 = i*256 + t;
        int j = idx2 & 7, l = (idx2 >> 3) & 63, nt = idx2 >> 9;
        int n2 = nt*16 + (l & 15), e = ((l >> 4) << 3) + j;
        WqkF[h*1024 + idx2] = f2bf(sQK[n2*32 + e]);
    }
}

// ---- anchor kernel: h_anchor = LN(x@Wa^T+b)+ve ; qk = Wqk @ h_anchor ; gs = softplus ----
__global__ __launch_bounds__(256, 3) void k_anchor(
    const float* __restrict__ xa, const float* __restrict__ gl,
    const float* __restrict__ b_anc, const float* __restrict__ g_anc,
    const float* __restrict__ be_anc, const float* __restrict__ ve,
    const float* __restrict__ Wgeom, const float* __restrict__ bgeom,
    const u16* __restrict__ WaB, const u16* __restrict__ WqkF,
    float* __restrict__ ha, float* __restrict__ qkws, float* __restrict__ gsws) {
    __shared__ __align__(16) char smem[32768 + 2048];
    const int t = threadIdx.x, w = t >> 6, l = t & 63;
    const int b0 = blockIdx.x * 64;

    stage_tile(xa + (size_t)b0 * 256, smem, t);
    __syncthreads();

    f32x4 acc[4][4];
    gemm_tile(smem, WaB, w, l, acc);

    float bn[4];
#pragma unroll
    for (int nt = 0; nt < 4; nt++) bn[nt] = b_anc[w*64 + nt*16 + (l & 15)];
#pragma unroll
    for (int mt = 0; mt < 4; mt++)
#pragma unroll
        for (int nt = 0; nt < 4; nt++)
#pragma unroll
            for (int r = 0; r < 4; r++) acc[mt][nt][r] += bn[nt];

    float2* PART = (float2*)(smem + 32768);
#pragma unroll
    for (int mt = 0; mt < 4; mt++)
#pragma unroll
        for (int r = 0; r < 4; r++) {
            float s  = acc[mt][0][r] + acc[mt][1][r] + acc[mt][2][r] + acc[mt][3][r];
            float qq = acc[mt][0][r]*acc[mt][0][r] + acc[mt][1][r]*acc[mt][1][r]
                     + acc[mt][2][r]*acc[mt][2][r] + acc[mt][3][r]*acc[mt][3][r];
#pragma unroll
            for (int m2 = 1; m2 < 16; m2 <<= 1) { s += __shfl_xor(s, m2); qq += __shfl_xor(qq, m2); }
            if ((l & 15) == 0) PART[w*64 + mt*16 + ((l >> 4) << 2) + r] = make_float2(s, qq);
        }
    __syncthreads();

    float gg[4], bb2[4], vv[4];
#pragma unroll
    for (int nt = 0; nt < 4; nt++) {
        int col = w*64 + nt*16 + (l & 15);
        gg[nt] = g_anc[col]; bb2[nt] = be_anc[col];
        vv[nt] = ve[((nt & 1) << 4) + (l & 15)];
    }
#pragma unroll
    for (int mt = 0; mt < 4; mt++)
#pragma unroll
        for (int r = 0; r < 4; r++) {
            int row = mt*16 + ((l >> 4) << 2) + r;
            float2 p0 = PART[row], p1 = PART[64+row], p2 = PART[128+row], p3 = PART[192+row];
            float mean = (p0.x+p1.x+p2.x+p3.x) * (1.f/256.f);
            float var  = (p0.y+p1.y+p2.y+p3.y) * (1.f/256.f) - mean*mean;
            float rs   = rsqrtf(var + 1e-5f);
#pragma unroll
            for (int nt = 0; nt < 4; nt++) {
                int col = w*64 + nt*16 + (l & 15);
                float x = (acc[mt][nt][r] - mean)*rs*gg[nt] + bb2[nt] + vv[nt];
                ha[(size_t)(b0+row)*256 + col] = x;
                *(u16*)(smem + row*512 + ((col*2) ^ ((row & 7) << 4))) = f2bf(x);
            }
        }
    __syncthreads();

    // qk projection (2 heads/wave): qk = Wqk @ h_anchor (scale folded into WqkF)
#pragma unroll
    for (int hh = 0; hh < 2; hh++) {
        int h = 2*w + hh;
        bf16x8 af[4];
#pragma unroll
        for (int mt = 0; mt < 4; mt++) {
            int row = mt*16 + (l & 15);
            int colb = h*64 + ((l >> 4) << 4);
            af[mt] = *(const bf16x8*)(smem + row*512 + (colb ^ ((row & 7) << 4)));
        }
        bf16x8 bf0 = *(const bf16x8*)(WqkF + ((h*2 + 0)*64 + l)*8);
        bf16x8 bf1 = *(const bf16x8*)(WqkF + ((h*2 + 1)*64 + l)*8);
        f32x4 qa[4][2];
#pragma unroll
        for (int mt = 0; mt < 4; mt++) {
            qa[mt][0] = (f32x4){0.f,0.f,0.f,0.f};
            qa[mt][1] = (f32x4){0.f,0.f,0.f,0.f};
            qa[mt][0] = __builtin_amdgcn_mfma_f32_16x16x32_bf16(af[mt], bf0, qa[mt][0], 0,0,0);
            qa[mt][1] = __builtin_amdgcn_mfma_f32_16x16x32_bf16(af[mt], bf1, qa[mt][1], 0,0,0);
        }
#pragma unroll
        for (int mt = 0; mt < 4; mt++)
#pragma unroll
            for (int nt = 0; nt < 2; nt++)
#pragma unroll
                for (int r = 0; r < 4; r++) {
                    int row = mt*16 + ((l >> 4) << 2) + r;
                    int d = nt*16 + (l & 15);
                    qkws[(size_t)(b0+row)*256 + h*32 + d] = qa[mt][nt][r];
                }
    }

    // geom_scale = softplus(g_local @ Wg^T + bg)
    for (int task = t; task < 512; task += 256) {
        int row = task >> 3, h = task & 7;
        const float* g = gl + (size_t)(b0+row)*32;
        float x = bgeom[h];
#pragma unroll
        for (int e = 0; e < 32; e++) x += g[e] * Wgeom[h*32 + e];
        gsws[(size_t)(b0+row)*8 + h] = (x > 20.f) ? x : log1pf(__expf(x));
    }
}

// ---- row body, explicitly instantiated 4x so st's live range never crosses the GEMM ----
template<bool PRE>
__device__ __forceinline__ void row_body(
    int b, char* smem, float2* PART, float* QKB,
    const float4* __restrict__ src4, const float* __restrict__ ew,
    const float* __restrict__ b_nei, const float* __restrict__ g_nei,
    const float* __restrict__ be_nei, const float* __restrict__ Wvo,
    const u16* __restrict__ WnB, const float* __restrict__ ha,
    const float* __restrict__ qkws, const float* __restrict__ gsws,
    float* __restrict__ outp, size_t ATT_OFF,
    int t, int w, int l, float4 st[16], float4& qkp) {

    // ---- tile write (cvt_pk bf16, swizzled); st dies here ----
#pragma unroll
    for (int i = 0; i < 8; i++) {
        int flat = i*2048 + t*8;
        int row = flat >> 8, colb = (flat & 255) * 2;
        float4 a = st[2*i], c = st[2*i+1];
        unsigned p0, p1, p2, p3;
        asm("v_cvt_pk_bf16_f32 %0,%1,%2" : "=v"(p0) : "v"(a.x), "v"(a.y));
        asm("v_cvt_pk_bf16_f32 %0,%1,%2" : "=v"(p1) : "v"(a.z), "v"(a.w));
        asm("v_cvt_pk_bf16_f32 %0,%1,%2" : "=v"(p2) : "v"(c.x), "v"(c.y));
        asm("v_cvt_pk_bf16_f32 %0,%1,%2" : "=v"(p3) : "v"(c.z), "v"(c.w));
        *(uint4*)(smem + row*512 + (colb ^ ((row & 7) << 4))) = make_uint4(p0, p1, p2, p3);
    }
    if (t < 64) ((float4*)QKB)[t] = qkp;
    __syncthreads();  // B1: tile + qk ready

    // ---- GEMM + bias (acc live; st dead) ----
    f32x4 acc[4][4];
    gemm_tile(smem, WnB, w, l, acc);
    float bn[4];
#pragma unroll
    for (int nt = 0; nt < 4; nt++) bn[nt] = b_nei[w*64 + nt*16 + (l & 15)];
#pragma unroll
    for (int mt = 0; mt < 4; mt++)
#pragma unroll
        for (int nt = 0; nt < 4; nt++)
#pragma unroll
            for (int rr = 0; rr < 4; rr++) acc[mt][nt][rr] += bn[nt];

    // ---- LN partials ----
#pragma unroll
    for (int mt = 0; mt < 4; mt++)
#pragma unroll
        for (int rr = 0; rr < 4; rr++) {
            float s  = acc[mt][0][rr] + acc[mt][1][rr] + acc[mt][2][rr] + acc[mt][3][rr];
            float qq = acc[mt][0][rr]*acc[mt][0][rr] + acc[mt][1][rr]*acc[mt][1][rr]
                     + acc[mt][2][rr]*acc[mt][2][rr] + acc[mt][3][rr]*acc[mt][3][rr];
#pragma unroll
            for (int m2 = 1; m2 < 16; m2 <<= 1) { s += __shfl_xor(s, m2); qq += __shfl_xor(qq, m2); }
            if ((l & 15) == 0) PART[w*64 + mt*16 + ((l >> 4) << 2) + rr] = make_float2(s, qq);
        }
    __syncthreads();  // B2: partials ready

    // ---- LN finalize + writeback into tile (acc dies here) ----
    float gg[4], bb2[4];
#pragma unroll
    for (int nt = 0; nt < 4; nt++) {
        int col = w*64 + nt*16 + (l & 15);
        gg[nt] = g_nei[col]; bb2[nt] = be_nei[col];
    }
#pragma unroll
    for (int mt = 0; mt < 4; mt++)
#pragma unroll
        for (int rr = 0; rr < 4; rr++) {
            int row = mt*16 + ((l >> 4) << 2) + rr;
            float2 p0 = PART[row], p1 = PART[64+row], p2 = PART[128+row], p3 = PART[192+row];
            float mean = (p0.x+p1.x+p2.x+p3.x) * (1.f/256.f);
            float var  = (p0.y+p1.y+p2.y+p3.y) * (1.f/256.f) - mean*mean;
            float rs   = rsqrtf(var + 1e-5f);
#pragma unroll
            for (int nt = 0; nt < 4; nt++) {
                int col = w*64 + nt*16 + (l & 15);
                float x = (acc[mt][nt][rr] - mean)*rs*gg[nt] + bb2[nt];
                *(u16*)(smem + row*512 + ((col*2) ^ ((row & 7) << 4))) = f2bf(x);
            }
        }
    __syncthreads();  // B3: h_nei ready

    // ---- issue next row's loads (acc dead; consumed at next copy's tile-write) ----
    if (PRE) {
        size_t Bn = (size_t)(b+1) * 4096;
#pragma unroll
        for (int i = 0; i < 8; i++) {
            st[2*i]   = src4[Bn + i*512 + t*2];
            st[2*i+1] = src4[Bn + i*512 + t*2 + 1];
        }
        if (t < 64) qkp = ((const float4*)qkws)[(size_t)(b+1)*64 + t];
    }

    // ---- scores + softmax (h = t>>5 half-wave group; k in {t&31, (t&31)+32}) ----
    const int h = t >> 5, k0 = t & 31, base = t & 32;
    float e0, e1;
    {
        const float gsv = gsws[(size_t)b*8 + h];
        float s0 = 0.f, s1 = 0.f;
        const int swz = (k0 & 7) << 4;
#pragma unroll
        for (int j = 0; j < 4; j++) {
            int colb = h*64 + j*16;
            u16x8 r0 = *(const u16x8*)(smem + k0*512       + (colb ^ swz));
            u16x8 r1 = *(const u16x8*)(smem + (k0+32)*512  + (colb ^ swz));
            float4 qa = ((const float4*)QKB)[h*8 + j*2];
            float4 qb = ((const float4*)QKB)[h*8 + j*2 + 1];
            s0 += bf2f(r0[0])*qa.x + bf2f(r0[1])*qa.y + bf2f(r0[2])*qa.z + bf2f(r0[3])*qa.w
                + bf2f(r0[4])*qb.x + bf2f(r0[5])*qb.y + bf2f(r0[6])*qb.z + bf2f(r0[7])*qb.w;
            s1 += bf2f(r1[0])*qa.x + bf2f(r1[1])*qa.y + bf2f(r1[2])*qa.z + bf2f(r1[3])*qa.w
                + bf2f(r1[4])*qb.x + bf2f(r1[5])*qb.y + bf2f(r1[6])*qb.z + bf2f(r1[7])*qb.w;
        }
        s0 += gsv * __logf(ew[(size_t)b*64 + k0] + 1e-6f);
        s1 += gsv * __logf(ew[(size_t)b*64 + k0 + 32] + 1e-6f);
        float mx = fmaxf(s0, s1);
#pragma unroll
        for (int m2 = 1; m2 < 32; m2 <<= 1) mx = fmaxf(mx, __shfl_xor(mx, m2));
        e0 = __expf(s0 - mx); e1 = __expf(s1 - mx);
        float sm = e0 + e1;
#pragma unroll
        for (int m2 = 1; m2 < 32; m2 <<= 1) sm += __shfl_xor(sm, m2);
        float inv = 1.f / sm;
        e0 *= inv; e1 *= inv;
        size_t ao = ATT_OFF + (size_t)b*512 + h*64;
        outp[ao + k0]      = e0;
        outp[ao + k0 + 32] = e1;
    }

    // ---- z = attn^T @ h_nei via half-wave shuffles ----
    float z = 0.f;
#pragma unroll
    for (int k = 0; k < 32; k++) {
        float a0 = __shfl(e0, base + k);
        float a1 = __shfl(e1, base + k);
        u16 h0 = *(const u16*)(smem + k*512      + ((2*t) ^ ((k & 7) << 4)));
        u16 h1 = *(const u16*)(smem + (k+32)*512 + ((2*t) ^ ((k & 7) << 4)));
        z += a0 * bf2f(h0) + a1 * bf2f(h1);
    }

    // ---- o = Wvo_h @ z_h + h_anchor via shuffles ----
    {
        const float4* wv4 = (const float4*)(Wvo + (h*32 + k0)*32);
        float o = 0.f;
#pragma unroll
        for (int e4 = 0; e4 < 8; e4++) {
            float4 wv = wv4[e4];
            o += wv.x * __shfl(z, base + e4*4)
               + wv.y * __shfl(z, base + e4*4 + 1)
               + wv.z * __shfl(z, base + e4*4 + 2)
               + wv.w * __shfl(z, base + e4*4 + 3);
        }
        o += ha[(size_t)b*256 + t];
        outp[(size_t)b*256 + t] = o;
    }
    __syncthreads();  // B4: all readers done before next tile-write
}

// ---- main kernel: 4 rows/block, manually instantiated bodies ----
#define ROWS 4
__global__ __launch_bounds__(256, 3) void k_main(
    const float* __restrict__ xn, const float* __restrict__ ew,
    const float* __restrict__ b_nei, const float* __restrict__ g_nei,
    const float* __restrict__ be_nei,
    const float* __restrict__ Wvo, const u16* __restrict__ WnB,
    const float* __restrict__ ha, const float* __restrict__ qkws,
    const float* __restrict__ gsws, float* __restrict__ outp, int Btot) {
    __shared__ __align__(16) char smem[32768 + 2048 + 1024];
    float2* PART = (float2*)(smem + 32768);       // 2 KB: LN partials
    float*  QKB  = (float*)(smem + 32768 + 2048); // 1 KB: qk[256]
    const int t = threadIdx.x, w = t >> 6, l = t & 63;
    const int b0 = blockIdx.x * ROWS;
    const float4* src4 = (const float4*)xn;
    const size_t ATT_OFF = (size_t)Btot * 256;

    float4 st[16]; float4 qkp;
    {   // prologue: issue row 0 loads
        size_t B4a = (size_t)b0 * 4096;
#pragma unroll
        for (int i = 0; i < 8; i++) {
            st[2*i]   = src4[B4a + i*512 + t*2];
            st[2*i+1] = src4[B4a + i*512 + t*2 + 1];
        }
        if (t < 64) qkp = ((const float4*)qkws)[(size_t)b0*64 + t];
    }

    row_body<true >(b0+0, smem, PART, QKB, src4, ew, b_nei, g_nei, be_nei, Wvo, WnB,
                    ha, qkws, gsws, outp, ATT_OFF, t, w, l, st, qkp);
    row_body<true >(b0+1, smem, PART, QKB, src4, ew, b_nei, g_nei, be_nei, Wvo, WnB,
                    ha, qkws, gsws, outp, ATT_OFF, t, w, l, st, qkp);
    row_body<true >(b0+2, smem, PART, QKB, src4, ew, b_nei, g_nei, be_nei, Wvo, WnB,
                    ha, qkws, gsws, outp, ATT_OFF, t, w, l, st, qkp);
    row_body<false>(b0+3, smem, PART, QKB, src4, ew, b_nei, g_nei, be_nei, Wvo, WnB,
                    ha, qkws, gsws, outp, ATT_OFF, t, w, l, st, qkp);
}

extern "C" void kernel_launch(void* const* d_in, const int* in_sizes, int n_in,
                              void* d_out, int out_size, void* d_ws, size_t ws_size,
                              hipStream_t stream) {
    const float* xa  = (const float*)d_in[0];
    const float* xn  = (const float*)d_in[1];
    const float* ew  = (const float*)d_in[2];
    const float* gl  = (const float*)d_in[3];
    const float* Wa  = (const float*)d_in[4];
    const float* ba  = (const float*)d_in[5];
    const float* ga  = (const float*)d_in[6];
    const float* bea = (const float*)d_in[7];
    const float* Wn  = (const float*)d_in[8];
    const float* bn  = (const float*)d_in[9];
    const float* gn  = (const float*)d_in[10];
    const float* ben = (const float*)d_in[11];
    const float* ve  = (const float*)d_in[12];
    const float* Wq  = (const float*)d_in[13];
    const float* Wk  = (const float*)d_in[14];
    const float* Wv  = (const float*)d_in[15];
    const float* Wo  = (const float*)d_in[16];
    const float* Wg  = (const float*)d_in[17];
    const float* bg  = (const float*)d_in[18];
    int B = in_sizes[0] / 256;

    char* ws = (char*)d_ws;
    u16*   WnB  = (u16*)(ws + 0);
    u16*   WaB  = (u16*)(ws + 131072);
    u16*   WqkF = (u16*)(ws + 262144);
    float* Wvo  = (float*)(ws + 278528);
    float* haP  = (float*)(ws + 311296);
    float* qkws = (float*)(ws + 311296 + 8388608);
    float* gsws = (float*)(ws + 311296 + 16777216);
    float* outp = (float*)d_out;

    hipLaunchKernelGGL(k_prep, dim3(256), dim3(256), 0, stream, Wa, Wn, WaB, WnB);
    hipLaunchKernelGGL(k_prep2, dim3(8), dim3(256), 0, stream, Wq, Wk, Wv, Wo, WqkF, Wvo);
    hipLaunchKernelGGL(k_anchor, dim3(B/64), dim3(256), 0, stream,
                       xa, gl, ba, ga, bea, ve, Wg, bg, WaB, WqkF, haP, qkws, gsws);
    hipLaunchKernelGGL(k_main, dim3(B/ROWS), dim3(256), 0, stream,
                       xn, ew, bn, gn, ben, Wvo, WnB, haP, qkws, gsws, outp, B);
}